// Round 5
// baseline (305.520 us; speedup 1.0000x reference)
//
#include <hip/hip_runtime.h>
#include <math.h>

#define CC 64
typedef _Float16 f16;
typedef _Float16 half8_t __attribute__((ext_vector_type(8)));
typedef _Float16 half4_t __attribute__((ext_vector_type(4)));
typedef float f32x4 __attribute__((ext_vector_type(4)));

__device__ __forceinline__ float silu_f(float v) {
    return v / (1.0f + __expf(-v));
}

// ---------------- K0: x = node_feats @ W_up  [N,64] @ [64,64] ----------------
__global__ void k_up(const float* __restrict__ nf, const float* __restrict__ Wup,
                     float* __restrict__ x, int N) {
    int tid = blockIdx.x * blockDim.x + threadIdx.x;
    if (tid >= N * CC) return;
    int n = tid >> 6;
    int j = tid & 63;
    const float* nfr = nf + (size_t)n * CC;
    float acc = 0.f;
#pragma unroll
    for (int k = 0; k < CC; ++k) acc += nfr[k] * Wup[k * CC + j];
    x[tid] = acc;
}

// ---------------- CSR build: histogram -> scan -> fill(+sph) ----------------
__global__ void k_hist(const int* __restrict__ rcv, int* __restrict__ cnt, int E) {
    int e = blockIdx.x * blockDim.x + threadIdx.x;
    if (e < E) atomicAdd(&cnt[rcv[e]], 1);
}

// single-pass scan: each thread owns a contiguous chunk; one shfl+LDS scan
__global__ __launch_bounds__(1024) void k_scan(const int* __restrict__ cnt,
        int* __restrict__ off, int* __restrict__ cur, int N) {
    __shared__ int wsum[16];
    int t = threadIdx.x;
    int wave = t >> 6, lane = t & 63;
    int per = (N + 1023) >> 10;
    int i0 = t * per;
    int s = 0;
    for (int j = 0; j < per; ++j) {
        int i = i0 + j;
        if (i < N) s += cnt[i];
    }
    int sc = s;
#pragma unroll
    for (int d = 1; d < 64; d <<= 1) {
        int u = __shfl_up(sc, d, 64);
        if (lane >= d) sc += u;
    }
    if (lane == 63) wsum[wave] = sc;
    __syncthreads();
    if (wave == 0) {
        int v = (lane < 16) ? wsum[lane] : 0;
        int s2 = v;
#pragma unroll
        for (int d = 1; d < 16; d <<= 1) {
            int u = __shfl_up(s2, d, 64);
            if (lane >= d) s2 += u;
        }
        if (lane < 16) wsum[lane] = s2;
    }
    __syncthreads();
    int base = ((wave > 0) ? wsum[wave - 1] : 0) + (sc - s);
    int run = base;
    for (int j = 0; j < per; ++j) {
        int i = i0 + j;
        if (i < N) { off[i] = run; cur[i] = run; run += cnt[i]; }
    }
    if (t == 1023) off[N] = run;
}

// fill CSR slots + fused spherical harmonics (written directly in CSR order)
__global__ void k_fill(const int* __restrict__ rcv, const int* __restrict__ snd,
                       const float* __restrict__ vec, int* __restrict__ cur,
                       int* __restrict__ pos, int* __restrict__ sndp,
                       float* __restrict__ yb, int E) {
    int e = blockIdx.x * blockDim.x + threadIdx.x;
    if (e >= E) return;
    int p = atomicAdd(&cur[rcv[e]], 1);
    pos[e] = p;
    sndp[p] = snd[e];

    float vx = vec[(size_t)e * 3 + 0];
    float vy = vec[(size_t)e * 3 + 1];
    float vz = vec[(size_t)e * 3 + 2];
    float nrm = sqrtf(vx * vx + vy * vy + vz * vz) + 1e-12f;
    float rinv = 1.0f / nrm;
    float ux = vx * rinv, uy = vy * rinv, uz = vz * rinv;

    const float s3 = 1.7320508075688772f;
    const float s5 = 2.2360679774997896f;
    const float s15 = 3.8729833462074170f;
    const float c1 = 2.0916500663351889f;
    const float c2 = 10.246950765959598f;
    const float c3 = 1.6201851746019651f;
    const float c4 = 1.3228756555322954f;

    float zz = uz * uz, xx = ux * ux, yy = uy * uy;
    float4 r0 = {1.0f, s3 * ux, s3 * uy, s3 * uz};
    float4 r1 = {s15 * ux * uy, s15 * uy * uz, 0.5f * s5 * (3.f * zz - 1.f),
                 s15 * ux * uz};
    float4 r2 = {0.5f * s15 * (xx - yy), c1 * uy * (3.f * xx - yy),
                 c2 * ux * uy * uz, c3 * uy * (5.f * zz - 1.f)};
    float4 r3 = {c4 * uz * (5.f * zz - 3.f), c3 * ux * (5.f * zz - 1.f),
                 0.5f * c2 * uz * (xx - yy), c1 * ux * (xx - yy)};
    float* yr = yb + (size_t)p * 16;
    *(float4*)(yr + 0)  = r0;
    *(float4*)(yr + 4)  = r1;
    *(float4*)(yr + 8)  = r2;
    *(float4*)(yr + 12) = r3;
}

// ---------------- K1: radial MLP via fp16 MFMA -> mixp [E,256] f16, CSR rows ----
__global__ __launch_bounds__(256) void k_mlp(const float* __restrict__ rad,
        const float* __restrict__ w1, const float* __restrict__ w2,
        const float* __restrict__ w3, const float* __restrict__ w4,
        const int* __restrict__ pos, f16* __restrict__ mixp, int E) {
    __shared__ f16 wB[64][72];
    __shared__ f16 wC[64][72];
    __shared__ f16 act[128][72];

    int t = threadIdx.x;
    int e0 = blockIdx.x * 128;
    int lane = t & 63;
    int wid = t >> 6;

    {
        int n = t & 63;
        int k0 = t >> 6;
        for (int k = k0; k < 64; k += 4) {
            wB[n][k] = (f16)w2[k * 64 + n];
            wC[n][k] = (f16)w3[k * 64 + n];
        }
    }

    // layer 1 in VALU
    {
        int i = t & 127;
        int jh = (t >> 7) * 32;
        int e = e0 + i;
        float r[8];
        if (e < E) {
#pragma unroll
            for (int k = 0; k < 8; ++k) r[k] = rad[(size_t)e * 8 + k];
        } else {
#pragma unroll
            for (int k = 0; k < 8; ++k) r[k] = 0.f;
        }
        float a[32];
#pragma unroll
        for (int j = 0; j < 32; ++j) a[j] = 0.f;
#pragma unroll
        for (int k = 0; k < 8; ++k) {
            float rv = r[k];
#pragma unroll
            for (int j = 0; j < 32; ++j) a[j] += rv * w1[k * 64 + jh + j];
        }
#pragma unroll
        for (int jj = 0; jj < 32; jj += 8) {
            half8_t h;
#pragma unroll
            for (int u = 0; u < 8; ++u) h[u] = (f16)silu_f(a[jj + u]);
            *(half8_t*)&act[i][jh + jj] = h;
        }
    }
    __syncthreads();

    int m0 = wid * 32;
    int fm = lane & 15;
    int q  = lane >> 4;

    auto loadA = [&](int mbase, int kc) -> half8_t {
        return *(const half8_t*)&act[mbase + fm][kc + q * 8];
    };

    // layer 2
    {
        half8_t a00 = loadA(m0, 0),      a01 = loadA(m0, 32);
        half8_t a10 = loadA(m0 + 16, 0), a11 = loadA(m0 + 16, 32);
#pragma unroll
        for (int nt = 0; nt < 4; ++nt) {
            half8_t b0 = *(const half8_t*)&wB[nt * 16 + fm][q * 8];
            half8_t b1 = *(const half8_t*)&wB[nt * 16 + fm][32 + q * 8];
            f32x4 c0 = {0.f, 0.f, 0.f, 0.f};
            c0 = __builtin_amdgcn_mfma_f32_16x16x32_f16(a00, b0, c0, 0, 0, 0);
            c0 = __builtin_amdgcn_mfma_f32_16x16x32_f16(a01, b1, c0, 0, 0, 0);
            f32x4 c1 = {0.f, 0.f, 0.f, 0.f};
            c1 = __builtin_amdgcn_mfma_f32_16x16x32_f16(a10, b0, c1, 0, 0, 0);
            c1 = __builtin_amdgcn_mfma_f32_16x16x32_f16(a11, b1, c1, 0, 0, 0);
#pragma unroll
            for (int r = 0; r < 4; ++r) {
                act[m0 + q * 4 + r][nt * 16 + fm]      = (f16)silu_f(c0[r]);
                act[m0 + 16 + q * 4 + r][nt * 16 + fm] = (f16)silu_f(c1[r]);
            }
        }
    }

    // layer 3
    {
        half8_t a00 = loadA(m0, 0),      a01 = loadA(m0, 32);
        half8_t a10 = loadA(m0 + 16, 0), a11 = loadA(m0 + 16, 32);
#pragma unroll
        for (int nt = 0; nt < 4; ++nt) {
            half8_t b0 = *(const half8_t*)&wC[nt * 16 + fm][q * 8];
            half8_t b1 = *(const half8_t*)&wC[nt * 16 + fm][32 + q * 8];
            f32x4 c0 = {0.f, 0.f, 0.f, 0.f};
            c0 = __builtin_amdgcn_mfma_f32_16x16x32_f16(a00, b0, c0, 0, 0, 0);
            c0 = __builtin_amdgcn_mfma_f32_16x16x32_f16(a01, b1, c0, 0, 0, 0);
            f32x4 c1 = {0.f, 0.f, 0.f, 0.f};
            c1 = __builtin_amdgcn_mfma_f32_16x16x32_f16(a10, b0, c1, 0, 0, 0);
            c1 = __builtin_amdgcn_mfma_f32_16x16x32_f16(a11, b1, c1, 0, 0, 0);
#pragma unroll
            for (int r = 0; r < 4; ++r) {
                act[m0 + q * 4 + r][nt * 16 + fm]      = (f16)silu_f(c0[r]);
                act[m0 + 16 + q * 4 + r][nt * 16 + fm] = (f16)silu_f(c1[r]);
            }
        }
    }

    // layer 4
    half8_t A00 = loadA(m0, 0),      A01 = loadA(m0, 32);
    half8_t A10 = loadA(m0 + 16, 0), A11 = loadA(m0 + 16, 32);

    auto do_l = [&](int l, f16 (*w)[72]) {
#pragma unroll
        for (int nt = 0; nt < 4; ++nt) {
            half8_t b0 = *(const half8_t*)&w[nt * 16 + fm][q * 8];
            half8_t b1 = *(const half8_t*)&w[nt * 16 + fm][32 + q * 8];
            f32x4 c0 = {0.f, 0.f, 0.f, 0.f};
            c0 = __builtin_amdgcn_mfma_f32_16x16x32_f16(A00, b0, c0, 0, 0, 0);
            c0 = __builtin_amdgcn_mfma_f32_16x16x32_f16(A01, b1, c0, 0, 0, 0);
            f32x4 c1 = {0.f, 0.f, 0.f, 0.f};
            c1 = __builtin_amdgcn_mfma_f32_16x16x32_f16(A10, b0, c1, 0, 0, 0);
            c1 = __builtin_amdgcn_mfma_f32_16x16x32_f16(A11, b1, c1, 0, 0, 0);
#pragma unroll
            for (int r = 0; r < 4; ++r) {
                act[m0 + q * 4 + r][nt * 16 + fm]      = (f16)c0[r];
                act[m0 + 16 + q * 4 + r][nt * 16 + fm] = (f16)c1[r];
            }
        }
#pragma unroll
        for (int it = 0; it < 4; ++it) {
            int row = (lane >> 3) + it * 8;
            int er = e0 + m0 + row;
            if (er < E) {
                int p = pos[er];
                half8_t v = *(const half8_t*)&act[m0 + row][(lane & 7) * 8];
                *(half8_t*)&mixp[(size_t)p * 256 + l * 64 + (lane & 7) * 8] = v;
            }
        }
    };

    __syncthreads();
    {
        int n = t & 63;
        int k0 = t >> 6;
        for (int k = k0; k < 64; k += 4) {
            wB[n][k] = (f16)w4[k * 256 + n];
            wC[n][k] = (f16)w4[k * 256 + 64 + n];
        }
    }
    __syncthreads();
    do_l(0, wB);
    do_l(1, wC);
    __syncthreads();
    {
        int n = t & 63;
        int k0 = t >> 6;
        for (int k = k0; k < 64; k += 4) {
            wB[n][k] = (f16)w4[k * 256 + 128 + n];
            wC[n][k] = (f16)w4[k * 256 + 192 + n];
        }
    }
    __syncthreads();
    do_l(2, wB);
    do_l(3, wC);
}

// ---------------- K2: gather, 4 nodes/wave, 4 channels/lane + fused down-proj ---
// lane = (group g, channel-quad cl): node n = base+g, channels 4cl..4cl+3.
// Vectorized loads: mix 4x8B, x 16B, y 4x16B (group-uniform broadcast).
// Epilogue: o -> LDS [c][16m] rows (stride 20 floats), 4x ds_read_b128
// broadcast per c, per-node sequential to keep LDS small.
#define GW 2   // waves per block
__global__ __launch_bounds__(128) void k_gather(const float* __restrict__ x,
        const f16* __restrict__ mixp, const float* __restrict__ yb,
        const int* __restrict__ sndp, const int* __restrict__ off,
        const float* __restrict__ Wd, float* __restrict__ out, int N) {
    __shared__ float sbuf[GW][1296];
    int wv = threadIdx.x >> 6;
    int lane = threadIdx.x & 63;
    int g = lane >> 4;
    int cl = lane & 15;
    int c0 = cl * 4;
    int nb = blockIdx.x * (GW * 4) + wv * 4;
    int n = nb + g;
    int beg = 0, end = 0;
    if (n < N) { beg = off[n]; end = off[n + 1]; }

    f32x4 o[16];
#pragma unroll
    for (int m = 0; m < 16; ++m) o[m] = (f32x4){0.f, 0.f, 0.f, 0.f};

#pragma unroll 2
    for (int i = beg; i < end; ++i) {
        int s = sndp[i];
        const f16* mr = mixp + (size_t)i * 256 + c0;
        half4_t h0 = *(const half4_t*)(mr);
        half4_t h1 = *(const half4_t*)(mr + 64);
        half4_t h2 = *(const half4_t*)(mr + 128);
        half4_t h3 = *(const half4_t*)(mr + 192);
        f32x4 sf = *(const f32x4*)&x[(size_t)s * 64 + c0];
        const float* yr = yb + (size_t)i * 16;
        f32x4 A  = *(const f32x4*)(yr + 0);
        f32x4 B  = *(const f32x4*)(yr + 4);
        f32x4 Cv = *(const f32x4*)(yr + 8);
        f32x4 D  = *(const f32x4*)(yr + 12);
        f32x4 t0 = sf * (f32x4){(float)h0.x, (float)h0.y, (float)h0.z, (float)h0.w};
        f32x4 t1 = sf * (f32x4){(float)h1.x, (float)h1.y, (float)h1.z, (float)h1.w};
        f32x4 t2 = sf * (f32x4){(float)h2.x, (float)h2.y, (float)h2.z, (float)h2.w};
        f32x4 t3 = sf * (f32x4){(float)h3.x, (float)h3.y, (float)h3.z, (float)h3.w};
        o[0]  += t0;
        o[1]  += t1 * A.y;
        o[2]  += t1 * A.z;
        o[3]  += t1 * A.w;
        o[4]  += t2 * B.x;
        o[5]  += t2 * B.y;
        o[6]  += t2 * B.z;
        o[7]  += t2 * B.w;
        o[8]  += t2 * Cv.x;
        o[9]  += t3 * Cv.y;
        o[10] += t3 * Cv.z;
        o[11] += t3 * Cv.w;
        o[12] += t3 * D.x;
        o[13] += t3 * D.y;
        o[14] += t3 * D.z;
        o[15] += t3 * D.w;
    }

    float* sw = sbuf[wv];
#pragma unroll 1
    for (int gg = 0; gg < 4; ++gg) {
        if (g == gg) {
            // transpose the 4ch x 16m register block into [c][m] LDS rows
#pragma unroll
            for (int j = 0; j < 4; ++j) {
#pragma unroll
                for (int a = 0; a < 4; ++a) {
                    f32x4 vq = {o[4 * a + 0][j], o[4 * a + 1][j],
                                o[4 * a + 2][j], o[4 * a + 3][j]};
                    *(f32x4*)&sw[(c0 + j) * 20 + 4 * a] = vq;
                }
            }
        }
        int ng = nb + gg;
        if (ng < N) {
            float dm[16];
#pragma unroll
            for (int m2 = 0; m2 < 16; ++m2) dm[m2] = 0.f;
#pragma unroll 1
            for (int c = 0; c < 64; ++c) {
                f32x4 q0 = *(const f32x4*)&sw[c * 20 + 0];
                f32x4 q1 = *(const f32x4*)&sw[c * 20 + 4];
                f32x4 q2 = *(const f32x4*)&sw[c * 20 + 8];
                f32x4 q3 = *(const f32x4*)&sw[c * 20 + 12];
                float w0  = Wd[c * 64 + lane];
                float w1r = Wd[4096 + c * 64 + lane];
                float w2r = Wd[8192 + c * 64 + lane];
                float w3r = Wd[12288 + c * 64 + lane];
                dm[0]  += q0[0] * w0;
                dm[1]  += q0[1] * w1r;
                dm[2]  += q0[2] * w1r;
                dm[3]  += q0[3] * w1r;
                dm[4]  += q1[0] * w2r;
                dm[5]  += q1[1] * w2r;
                dm[6]  += q1[2] * w2r;
                dm[7]  += q1[3] * w2r;
                dm[8]  += q2[0] * w2r;
                dm[9]  += q2[1] * w3r;
                dm[10] += q2[2] * w3r;
                dm[11] += q2[3] * w3r;
                dm[12] += q3[0] * w3r;
                dm[13] += q3[1] * w3r;
                dm[14] += q3[2] * w3r;
                dm[15] += q3[3] * w3r;
            }
            float* outr = out + (size_t)ng * 1024;
            outr[lane] = 0.25f * dm[0];
#pragma unroll
            for (int m2 = 0; m2 < 3; ++m2) outr[64 + lane * 3 + m2] = 0.25f * dm[1 + m2];
#pragma unroll
            for (int m2 = 0; m2 < 5; ++m2) outr[256 + lane * 5 + m2] = 0.25f * dm[4 + m2];
#pragma unroll
            for (int m2 = 0; m2 < 7; ++m2) outr[576 + lane * 7 + m2] = 0.25f * dm[9 + m2];
        }
    }
}

extern "C" void kernel_launch(void* const* d_in, const int* in_sizes, int n_in,
                              void* d_out, int out_size, void* d_ws, size_t ws_size,
                              hipStream_t stream) {
    const float* vectors    = (const float*)d_in[0];
    const float* node_feats = (const float*)d_in[1];
    const float* radial     = (const float*)d_in[2];
    const float* W_up       = (const float*)d_in[3];
    const float* w1         = (const float*)d_in[4];
    const float* w2         = (const float*)d_in[5];
    const float* w3         = (const float*)d_in[6];
    const float* w4         = (const float*)d_in[7];
    const float* Wd         = (const float*)d_in[8];
    const int*   snd        = (const int*)d_in[9];
    const int*   rcv        = (const int*)d_in[10];
    float* out = (float*)d_out;

    int E = in_sizes[9];
    int N = in_sizes[1] / CC;

    // ws: x [N*64]f | yb [E*16]f | mixp [E*256]f16 | cnt [N] | off [N+1] | cur [N] | pos [E] | sndp [E]
    float* ws   = (float*)d_ws;
    float* x    = ws;
    float* yb   = x + (size_t)N * 64;
    f16*   mixp = (f16*)(yb + (size_t)E * 16);
    int*   cnt  = (int*)((char*)mixp + (size_t)E * 256 * sizeof(f16));
    int*   off  = cnt + N;
    int*   cur  = off + (N + 1);
    int*   pos  = cur + N;
    int*   sndp = pos + E;

    hipMemsetAsync(cnt, 0, (size_t)N * sizeof(int), stream);

    k_up<<<(N * CC + 255) / 256, 256, 0, stream>>>(node_feats, W_up, x, N);
    k_hist<<<(E + 255) / 256, 256, 0, stream>>>(rcv, cnt, E);
    k_scan<<<1, 1024, 0, stream>>>(cnt, off, cur, N);
    k_fill<<<(E + 255) / 256, 256, 0, stream>>>(rcv, snd, vectors, cur, pos, sndp, yb, E);
    k_mlp<<<(E + 127) / 128, 256, 0, stream>>>(radial, w1, w2, w3, w4, pos, mixp, E);
    k_gather<<<(N + GW * 4 - 1) / (GW * 4), GW * 64, 0, stream>>>(x, mixp, yb, sndp, off, Wd, out, N);
}

// Round 6
// 248.095 us; speedup vs baseline: 1.2315x; 1.2315x over previous
//
#include <hip/hip_runtime.h>
#include <math.h>

#define CC 64
typedef _Float16 f16;
typedef _Float16 half8_t __attribute__((ext_vector_type(8)));
typedef float f32x4 __attribute__((ext_vector_type(4)));

__device__ __forceinline__ float silu_f(float v) {
    return v / (1.0f + __expf(-v));
}

// ---------------- K0: x = node_feats @ W_up  [N,64] @ [64,64] ----------------
__global__ void k_up(const float* __restrict__ nf, const float* __restrict__ Wup,
                     float* __restrict__ x, int N) {
    int tid = blockIdx.x * blockDim.x + threadIdx.x;
    if (tid >= N * CC) return;
    int n = tid >> 6;
    int j = tid & 63;
    const float* nfr = nf + (size_t)n * CC;
    float acc = 0.f;
#pragma unroll
    for (int k = 0; k < CC; ++k) acc += nfr[k] * Wup[k * CC + j];
    x[tid] = acc;
}

// ---------------- CSR build: histogram -> scan -> fill(+sph) ----------------
__global__ void k_hist(const int* __restrict__ rcv, int* __restrict__ cnt, int E) {
    int e = blockIdx.x * blockDim.x + threadIdx.x;
    if (e < E) atomicAdd(&cnt[rcv[e]], 1);
}

// single-pass scan: each thread owns a contiguous chunk; one shfl+LDS scan
__global__ __launch_bounds__(1024) void k_scan(const int* __restrict__ cnt,
        int* __restrict__ off, int* __restrict__ cur, int N) {
    __shared__ int wsum[16];
    int t = threadIdx.x;
    int wave = t >> 6, lane = t & 63;
    int per = (N + 1023) >> 10;
    int i0 = t * per;
    int s = 0;
    for (int j = 0; j < per; ++j) {
        int i = i0 + j;
        if (i < N) s += cnt[i];
    }
    int sc = s;
#pragma unroll
    for (int d = 1; d < 64; d <<= 1) {
        int u = __shfl_up(sc, d, 64);
        if (lane >= d) sc += u;
    }
    if (lane == 63) wsum[wave] = sc;
    __syncthreads();
    if (wave == 0) {
        int v = (lane < 16) ? wsum[lane] : 0;
        int s2 = v;
#pragma unroll
        for (int d = 1; d < 16; d <<= 1) {
            int u = __shfl_up(s2, d, 64);
            if (lane >= d) s2 += u;
        }
        if (lane < 16) wsum[lane] = s2;
    }
    __syncthreads();
    int base = ((wave > 0) ? wsum[wave - 1] : 0) + (sc - s);
    int run = base;
    for (int j = 0; j < per; ++j) {
        int i = i0 + j;
        if (i < N) { off[i] = run; cur[i] = run; run += cnt[i]; }
    }
    if (t == 1023) off[N] = run;
}

// fill CSR slots + fused spherical harmonics (written directly in CSR order)
__global__ void k_fill(const int* __restrict__ rcv, const int* __restrict__ snd,
                       const float* __restrict__ vec, int* __restrict__ cur,
                       int* __restrict__ eid, int* __restrict__ sndp,
                       float* __restrict__ yb, int E) {
    int e = blockIdx.x * blockDim.x + threadIdx.x;
    if (e >= E) return;
    int p = atomicAdd(&cur[rcv[e]], 1);
    eid[p] = e;
    sndp[p] = snd[e];

    float vx = vec[(size_t)e * 3 + 0];
    float vy = vec[(size_t)e * 3 + 1];
    float vz = vec[(size_t)e * 3 + 2];
    float nrm = sqrtf(vx * vx + vy * vy + vz * vz) + 1e-12f;
    float rinv = 1.0f / nrm;
    float ux = vx * rinv, uy = vy * rinv, uz = vz * rinv;

    const float s3 = 1.7320508075688772f;
    const float s5 = 2.2360679774997896f;
    const float s15 = 3.8729833462074170f;
    const float c1 = 2.0916500663351889f;
    const float c2 = 10.246950765959598f;
    const float c3 = 1.6201851746019651f;
    const float c4 = 1.3228756555322954f;

    float zz = uz * uz, xx = ux * ux, yy = uy * uy;
    float4 r0 = {1.0f, s3 * ux, s3 * uy, s3 * uz};
    float4 r1 = {s15 * ux * uy, s15 * uy * uz, 0.5f * s5 * (3.f * zz - 1.f),
                 s15 * ux * uz};
    float4 r2 = {0.5f * s15 * (xx - yy), c1 * uy * (3.f * xx - yy),
                 c2 * ux * uy * uz, c3 * uy * (5.f * zz - 1.f)};
    float4 r3 = {c4 * uz * (5.f * zz - 3.f), c3 * ux * (5.f * zz - 1.f),
                 0.5f * c2 * uz * (xx - yy), c1 * ux * (xx - yy)};
    float* yr = yb + (size_t)p * 16;
    *(float4*)(yr + 0)  = r0;
    *(float4*)(yr + 4)  = r1;
    *(float4*)(yr + 8)  = r2;
    *(float4*)(yr + 12) = r3;
}

// ---------------- K1: radial MLP via fp16 MFMA -> mixp [E,256] f16, CSR rows ----
// Processes CSR rows directly: rad gathered via eid (random 32B loads, L2-
// friendly), mixp stores fully coalesced.
__global__ __launch_bounds__(256) void k_mlp(const float* __restrict__ rad,
        const float* __restrict__ w1, const float* __restrict__ w2,
        const float* __restrict__ w3, const float* __restrict__ w4,
        const int* __restrict__ eid, f16* __restrict__ mixp, int E) {
    __shared__ f16 wB[64][72];
    __shared__ f16 wC[64][72];
    __shared__ f16 act[128][72];

    int t = threadIdx.x;
    int e0 = blockIdx.x * 128;
    int lane = t & 63;
    int wid = t >> 6;

    {
        int n = t & 63;
        int k0 = t >> 6;
        for (int k = k0; k < 64; k += 4) {
            wB[n][k] = (f16)w2[k * 64 + n];
            wC[n][k] = (f16)w3[k * 64 + n];
        }
    }

    // layer 1 in VALU: thread = CSR row
    {
        int i = t & 127;
        int jh = (t >> 7) * 32;
        int ci = e0 + i;
        float r[8];
        if (ci < E) {
            int e = eid[ci];
#pragma unroll
            for (int k = 0; k < 8; ++k) r[k] = rad[(size_t)e * 8 + k];
        } else {
#pragma unroll
            for (int k = 0; k < 8; ++k) r[k] = 0.f;
        }
        float a[32];
#pragma unroll
        for (int j = 0; j < 32; ++j) a[j] = 0.f;
#pragma unroll
        for (int k = 0; k < 8; ++k) {
            float rv = r[k];
#pragma unroll
            for (int j = 0; j < 32; ++j) a[j] += rv * w1[k * 64 + jh + j];
        }
#pragma unroll
        for (int jj = 0; jj < 32; jj += 8) {
            half8_t h;
#pragma unroll
            for (int u = 0; u < 8; ++u) h[u] = (f16)silu_f(a[jj + u]);
            *(half8_t*)&act[i][jh + jj] = h;
        }
    }
    __syncthreads();

    int m0 = wid * 32;
    int fm = lane & 15;
    int q  = lane >> 4;

    auto loadA = [&](int mbase, int kc) -> half8_t {
        return *(const half8_t*)&act[mbase + fm][kc + q * 8];
    };

    // layer 2
    {
        half8_t a00 = loadA(m0, 0),      a01 = loadA(m0, 32);
        half8_t a10 = loadA(m0 + 16, 0), a11 = loadA(m0 + 16, 32);
#pragma unroll
        for (int nt = 0; nt < 4; ++nt) {
            half8_t b0 = *(const half8_t*)&wB[nt * 16 + fm][q * 8];
            half8_t b1 = *(const half8_t*)&wB[nt * 16 + fm][32 + q * 8];
            f32x4 c0 = {0.f, 0.f, 0.f, 0.f};
            c0 = __builtin_amdgcn_mfma_f32_16x16x32_f16(a00, b0, c0, 0, 0, 0);
            c0 = __builtin_amdgcn_mfma_f32_16x16x32_f16(a01, b1, c0, 0, 0, 0);
            f32x4 c1 = {0.f, 0.f, 0.f, 0.f};
            c1 = __builtin_amdgcn_mfma_f32_16x16x32_f16(a10, b0, c1, 0, 0, 0);
            c1 = __builtin_amdgcn_mfma_f32_16x16x32_f16(a11, b1, c1, 0, 0, 0);
#pragma unroll
            for (int r = 0; r < 4; ++r) {
                act[m0 + q * 4 + r][nt * 16 + fm]      = (f16)silu_f(c0[r]);
                act[m0 + 16 + q * 4 + r][nt * 16 + fm] = (f16)silu_f(c1[r]);
            }
        }
    }

    // layer 3
    {
        half8_t a00 = loadA(m0, 0),      a01 = loadA(m0, 32);
        half8_t a10 = loadA(m0 + 16, 0), a11 = loadA(m0 + 16, 32);
#pragma unroll
        for (int nt = 0; nt < 4; ++nt) {
            half8_t b0 = *(const half8_t*)&wC[nt * 16 + fm][q * 8];
            half8_t b1 = *(const half8_t*)&wC[nt * 16 + fm][32 + q * 8];
            f32x4 c0 = {0.f, 0.f, 0.f, 0.f};
            c0 = __builtin_amdgcn_mfma_f32_16x16x32_f16(a00, b0, c0, 0, 0, 0);
            c0 = __builtin_amdgcn_mfma_f32_16x16x32_f16(a01, b1, c0, 0, 0, 0);
            f32x4 c1 = {0.f, 0.f, 0.f, 0.f};
            c1 = __builtin_amdgcn_mfma_f32_16x16x32_f16(a10, b0, c1, 0, 0, 0);
            c1 = __builtin_amdgcn_mfma_f32_16x16x32_f16(a11, b1, c1, 0, 0, 0);
#pragma unroll
            for (int r = 0; r < 4; ++r) {
                act[m0 + q * 4 + r][nt * 16 + fm]      = (f16)silu_f(c0[r]);
                act[m0 + 16 + q * 4 + r][nt * 16 + fm] = (f16)silu_f(c1[r]);
            }
        }
    }

    // layer 4
    half8_t A00 = loadA(m0, 0),      A01 = loadA(m0, 32);
    half8_t A10 = loadA(m0 + 16, 0), A11 = loadA(m0 + 16, 32);

    auto do_l = [&](int l, f16 (*w)[72]) {
#pragma unroll
        for (int nt = 0; nt < 4; ++nt) {
            half8_t b0 = *(const half8_t*)&w[nt * 16 + fm][q * 8];
            half8_t b1 = *(const half8_t*)&w[nt * 16 + fm][32 + q * 8];
            f32x4 c0 = {0.f, 0.f, 0.f, 0.f};
            c0 = __builtin_amdgcn_mfma_f32_16x16x32_f16(A00, b0, c0, 0, 0, 0);
            c0 = __builtin_amdgcn_mfma_f32_16x16x32_f16(A01, b1, c0, 0, 0, 0);
            f32x4 c1 = {0.f, 0.f, 0.f, 0.f};
            c1 = __builtin_amdgcn_mfma_f32_16x16x32_f16(A10, b0, c1, 0, 0, 0);
            c1 = __builtin_amdgcn_mfma_f32_16x16x32_f16(A11, b1, c1, 0, 0, 0);
#pragma unroll
            for (int r = 0; r < 4; ++r) {
                act[m0 + q * 4 + r][nt * 16 + fm]      = (f16)c0[r];
                act[m0 + 16 + q * 4 + r][nt * 16 + fm] = (f16)c1[r];
            }
        }
        // coalesced half8 stores: rows are CSR indices
#pragma unroll
        for (int it = 0; it < 4; ++it) {
            int row = (lane >> 3) + it * 8;
            int ci = e0 + m0 + row;
            if (ci < E) {
                half8_t v = *(const half8_t*)&act[m0 + row][(lane & 7) * 8];
                *(half8_t*)&mixp[(size_t)ci * 256 + l * 64 + (lane & 7) * 8] = v;
            }
        }
    };

    __syncthreads();
    {
        int n = t & 63;
        int k0 = t >> 6;
        for (int k = k0; k < 64; k += 4) {
            wB[n][k] = (f16)w4[k * 256 + n];
            wC[n][k] = (f16)w4[k * 256 + 64 + n];
        }
    }
    __syncthreads();
    do_l(0, wB);
    do_l(1, wC);
    __syncthreads();
    {
        int n = t & 63;
        int k0 = t >> 6;
        for (int k = k0; k < 64; k += 4) {
            wB[n][k] = (f16)w4[k * 256 + 128 + n];
            wC[n][k] = (f16)w4[k * 256 + 192 + n];
        }
    }
    __syncthreads();
    do_l(2, wB);
    do_l(3, wC);
}

// ---------------- K2: gather, 1 node/wave, packed-fp32 down-proj epilogue ------
__global__ __launch_bounds__(256) void k_gather(const float* __restrict__ x,
        const f16* __restrict__ mixp, const float* __restrict__ yb,
        const int* __restrict__ sndp, const int* __restrict__ off,
        const float* __restrict__ Wd, float* __restrict__ out, int N) {
    __shared__ float sbuf[4][64 * 20];
    int wv = threadIdx.x >> 6;
    int lane = threadIdx.x & 63;
    int n = blockIdx.x * 4 + wv;
    if (n >= N) return;

    float o[16];
#pragma unroll
    for (int i = 0; i < 16; ++i) o[i] = 0.f;

    auto process = [&](int i) {
        int s = sndp[i];
        const float* yr = yb + (size_t)i * 16;
        float4 A = *(const float4*)(yr + 0);
        float4 B = *(const float4*)(yr + 4);
        float4 Cv = *(const float4*)(yr + 8);
        float4 D = *(const float4*)(yr + 12);
        float sf = x[(size_t)s * 64 + lane];
        const f16* mr = mixp + (size_t)i * 256;
        float t0 = sf * (float)mr[lane];
        float t1 = sf * (float)mr[64 + lane];
        float t2 = sf * (float)mr[128 + lane];
        float t3 = sf * (float)mr[192 + lane];
        o[0]  += t0;
        o[1]  += t1 * A.y;
        o[2]  += t1 * A.z;
        o[3]  += t1 * A.w;
        o[4]  += t2 * B.x;
        o[5]  += t2 * B.y;
        o[6]  += t2 * B.z;
        o[7]  += t2 * B.w;
        o[8]  += t2 * Cv.x;
        o[9]  += t3 * Cv.y;
        o[10] += t3 * Cv.z;
        o[11] += t3 * Cv.w;
        o[12] += t3 * D.x;
        o[13] += t3 * D.y;
        o[14] += t3 * D.z;
        o[15] += t3 * D.w;
    };

    int beg = off[n], end = off[n + 1];
    int i = beg;
    for (; i + 1 < end; i += 2) { process(i); process(i + 1); }
    if (i < end) process(i);

    // wave-private transpose: lane's o[16] -> sw[lane*20 + m], b128 writes
    float* sw = sbuf[wv];
#pragma unroll
    for (int a = 0; a < 4; ++a) {
        f32x4 vq = {o[4 * a + 0], o[4 * a + 1], o[4 * a + 2], o[4 * a + 3]};
        *(f32x4*)&sw[lane * 20 + 4 * a] = vq;
    }

    // down-proj: per c, 4 b128 broadcasts + packed-f32 fma quads
    f32x4 dA = {0.f, 0.f, 0.f, 0.f}, dB = dA, dC = dA, dD = dA;
#pragma unroll 1
    for (int c = 0; c < 64; ++c) {
        f32x4 q0 = *(const f32x4*)&sw[c * 20 + 0];
        f32x4 q1 = *(const f32x4*)&sw[c * 20 + 4];
        f32x4 q2 = *(const f32x4*)&sw[c * 20 + 8];
        f32x4 q3 = *(const f32x4*)&sw[c * 20 + 12];
        float w0  = Wd[c * 64 + lane];
        float w1r = Wd[4096 + c * 64 + lane];
        float w2r = Wd[8192 + c * 64 + lane];
        float w3r = Wd[12288 + c * 64 + lane];
        f32x4 wA = {w0, w1r, w1r, w1r};
        f32x4 wC4 = {w2r, w3r, w3r, w3r};
        dA += q0 * wA;
        dB += q1 * w2r;
        dC += q2 * wC4;
        dD += q3 * w3r;
    }

    float* outr = out + (size_t)n * 1024;
    outr[lane] = 0.25f * dA[0];
#pragma unroll
    for (int m = 0; m < 3; ++m) outr[64 + lane * 3 + m] = 0.25f * dA[1 + m];
    // l=2 positions 4..8 = dB[0..3], dC[0]
    outr[256 + lane * 5 + 0] = 0.25f * dB[0];
    outr[256 + lane * 5 + 1] = 0.25f * dB[1];
    outr[256 + lane * 5 + 2] = 0.25f * dB[2];
    outr[256 + lane * 5 + 3] = 0.25f * dB[3];
    outr[256 + lane * 5 + 4] = 0.25f * dC[0];
    // l=3 positions 9..15 = dC[1..3], dD[0..3]
    outr[576 + lane * 7 + 0] = 0.25f * dC[1];
    outr[576 + lane * 7 + 1] = 0.25f * dC[2];
    outr[576 + lane * 7 + 2] = 0.25f * dC[3];
    outr[576 + lane * 7 + 3] = 0.25f * dD[0];
    outr[576 + lane * 7 + 4] = 0.25f * dD[1];
    outr[576 + lane * 7 + 5] = 0.25f * dD[2];
    outr[576 + lane * 7 + 6] = 0.25f * dD[3];
}

extern "C" void kernel_launch(void* const* d_in, const int* in_sizes, int n_in,
                              void* d_out, int out_size, void* d_ws, size_t ws_size,
                              hipStream_t stream) {
    const float* vectors    = (const float*)d_in[0];
    const float* node_feats = (const float*)d_in[1];
    const float* radial     = (const float*)d_in[2];
    const float* W_up       = (const float*)d_in[3];
    const float* w1         = (const float*)d_in[4];
    const float* w2         = (const float*)d_in[5];
    const float* w3         = (const float*)d_in[6];
    const float* w4         = (const float*)d_in[7];
    const float* Wd         = (const float*)d_in[8];
    const int*   snd        = (const int*)d_in[9];
    const int*   rcv        = (const int*)d_in[10];
    float* out = (float*)d_out;

    int E = in_sizes[9];
    int N = in_sizes[1] / CC;

    // ws: x [N*64]f | yb [E*16]f | mixp [E*256]f16 | cnt [N] | off [N+1] | cur [N] | eid [E] | sndp [E]
    float* ws   = (float*)d_ws;
    float* x    = ws;
    float* yb   = x + (size_t)N * 64;
    f16*   mixp = (f16*)(yb + (size_t)E * 16);
    int*   cnt  = (int*)((char*)mixp + (size_t)E * 256 * sizeof(f16));
    int*   off  = cnt + N;
    int*   cur  = off + (N + 1);
    int*   eid  = cur + N;
    int*   sndp = eid + E;

    hipMemsetAsync(cnt, 0, (size_t)N * sizeof(int), stream);

    k_up<<<(N * CC + 255) / 256, 256, 0, stream>>>(node_feats, W_up, x, N);
    k_hist<<<(E + 255) / 256, 256, 0, stream>>>(rcv, cnt, E);
    k_scan<<<1, 1024, 0, stream>>>(cnt, off, cur, N);
    k_fill<<<(E + 255) / 256, 256, 0, stream>>>(rcv, snd, vectors, cur, eid, sndp, yb, E);
    k_mlp<<<(E + 127) / 128, 256, 0, stream>>>(radial, w1, w2, w3, w4, eid, mixp, E);
    k_gather<<<(N + 3) / 4, 256, 0, stream>>>(x, mixp, yb, sndp, off, Wd, out, N);
}

// Round 7
// 246.857 us; speedup vs baseline: 1.2376x; 1.0050x over previous
//
#include <hip/hip_runtime.h>
#include <math.h>

#define CC 64
typedef _Float16 f16;
typedef _Float16 half8_t __attribute__((ext_vector_type(8)));
typedef float f32x4 __attribute__((ext_vector_type(4)));

__device__ __forceinline__ float silu_f(float v) {
    return v / (1.0f + __expf(-v));
}

// ---------------- K0: x = node_feats @ W_up  [N,64] @ [64,64] ----------------
__global__ void k_up(const float* __restrict__ nf, const float* __restrict__ Wup,
                     float* __restrict__ x, int N) {
    int tid = blockIdx.x * blockDim.x + threadIdx.x;
    if (tid >= N * CC) return;
    int n = tid >> 6;
    int j = tid & 63;
    const float* nfr = nf + (size_t)n * CC;
    float acc = 0.f;
#pragma unroll
    for (int k = 0; k < CC; ++k) acc += nfr[k] * Wup[k * CC + j];
    x[tid] = acc;
}

// ---------------- K_wt: precompute fp16 transposed weights (once) ------------
// wT1 [64n][32k] (k>=8 zero) | wT2,wT3 [64n][64k] | wT4 [4l][64n][64k]
__global__ void k_wt(const float* __restrict__ w1, const float* __restrict__ w2,
                     const float* __restrict__ w3, const float* __restrict__ w4,
                     f16* __restrict__ wT1, f16* __restrict__ wT2,
                     f16* __restrict__ wT3, f16* __restrict__ wT4) {
    int i = blockIdx.x * 256 + threadIdx.x;
    if (i < 2048) {
        int n = i >> 5, k = i & 31;
        wT1[i] = (k < 8) ? (f16)w1[k * 64 + n] : (f16)0.f;
    } else if (i < 6144) {
        int j = i - 2048; int n = j >> 6, k = j & 63;
        wT2[j] = (f16)w2[k * 64 + n];
    } else if (i < 10240) {
        int j = i - 6144; int n = j >> 6, k = j & 63;
        wT3[j] = (f16)w3[k * 64 + n];
    } else if (i < 26624) {
        int j = i - 10240; int l = j >> 12; int r = j & 4095;
        int n = r >> 6, k = r & 63;
        wT4[j] = (f16)w4[k * 256 + l * 64 + n];
    }
}

// ---------------- CSR build: histogram -> scan -> fill(+sph) ----------------
__global__ void k_hist(const int* __restrict__ rcv, int* __restrict__ cnt, int E) {
    int e = blockIdx.x * blockDim.x + threadIdx.x;
    if (e < E) atomicAdd(&cnt[rcv[e]], 1);
}

__global__ __launch_bounds__(1024) void k_scan(const int* __restrict__ cnt,
        int* __restrict__ off, int* __restrict__ cur, int N) {
    __shared__ int wsum[16];
    int t = threadIdx.x;
    int wave = t >> 6, lane = t & 63;
    int per = (N + 1023) >> 10;
    int i0 = t * per;
    int s = 0;
    for (int j = 0; j < per; ++j) {
        int i = i0 + j;
        if (i < N) s += cnt[i];
    }
    int sc = s;
#pragma unroll
    for (int d = 1; d < 64; d <<= 1) {
        int u = __shfl_up(sc, d, 64);
        if (lane >= d) sc += u;
    }
    if (lane == 63) wsum[wave] = sc;
    __syncthreads();
    if (wave == 0) {
        int v = (lane < 16) ? wsum[lane] : 0;
        int s2 = v;
#pragma unroll
        for (int d = 1; d < 16; d <<= 1) {
            int u = __shfl_up(s2, d, 64);
            if (lane >= d) s2 += u;
        }
        if (lane < 16) wsum[lane] = s2;
    }
    __syncthreads();
    int base = ((wave > 0) ? wsum[wave - 1] : 0) + (sc - s);
    int run = base;
    for (int j = 0; j < per; ++j) {
        int i = i0 + j;
        if (i < N) { off[i] = run; cur[i] = run; run += cnt[i]; }
    }
    if (t == 1023) off[N] = run;
}

// fill CSR slots + fused spherical harmonics (written directly in CSR order)
__global__ void k_fill(const int* __restrict__ rcv, const int* __restrict__ snd,
                       const float* __restrict__ vec, int* __restrict__ cur,
                       int* __restrict__ eid, int* __restrict__ sndp,
                       float* __restrict__ yb, int E) {
    int e = blockIdx.x * blockDim.x + threadIdx.x;
    if (e >= E) return;
    int p = atomicAdd(&cur[rcv[e]], 1);
    eid[p] = e;
    sndp[p] = snd[e];

    float vx = vec[(size_t)e * 3 + 0];
    float vy = vec[(size_t)e * 3 + 1];
    float vz = vec[(size_t)e * 3 + 2];
    float nrm = sqrtf(vx * vx + vy * vy + vz * vz) + 1e-12f;
    float rinv = 1.0f / nrm;
    float ux = vx * rinv, uy = vy * rinv, uz = vz * rinv;

    const float s3 = 1.7320508075688772f;
    const float s5 = 2.2360679774997896f;
    const float s15 = 3.8729833462074170f;
    const float c1 = 2.0916500663351889f;
    const float c2 = 10.246950765959598f;
    const float c3 = 1.6201851746019651f;
    const float c4 = 1.3228756555322954f;

    float zz = uz * uz, xx = ux * ux, yy = uy * uy;
    float4 r0 = {1.0f, s3 * ux, s3 * uy, s3 * uz};
    float4 r1 = {s15 * ux * uy, s15 * uy * uz, 0.5f * s5 * (3.f * zz - 1.f),
                 s15 * ux * uz};
    float4 r2 = {0.5f * s15 * (xx - yy), c1 * uy * (3.f * xx - yy),
                 c2 * ux * uy * uz, c3 * uy * (5.f * zz - 1.f)};
    float4 r3 = {c4 * uz * (5.f * zz - 3.f), c3 * ux * (5.f * zz - 1.f),
                 0.5f * c2 * uz * (xx - yy), c1 * ux * (xx - yy)};
    float* yr = yb + (size_t)p * 16;
    *(float4*)(yr + 0)  = r0;
    *(float4*)(yr + 4)  = r1;
    *(float4*)(yr + 8)  = r2;
    *(float4*)(yr + 12) = r3;
}

// ---------------- K1: radial MLP, all-MFMA, weights from global (L1-hot) -----
// block = 256 thr = 4 waves; wave owns 32 CSR rows (2 m-tiles). act is the
// only LDS (wave-private rows) -> ZERO barriers. B-fragments read straight
// from precomputed wT arrays in global memory (identical across waves -> L1).
__global__ __launch_bounds__(256) void k_mlp(const float* __restrict__ rad,
        const f16* __restrict__ wT1, const f16* __restrict__ wT2,
        const f16* __restrict__ wT3, const f16* __restrict__ wT4,
        const int* __restrict__ eid, f16* __restrict__ mixp, int E) {
    __shared__ f16 act[128][72];

    int t = threadIdx.x;
    int e0 = blockIdx.x * 128;
    int lane = t & 63;
    int wid = t >> 6;
    int m0 = wid * 32;
    int fm = lane & 15;
    int q  = lane >> 4;

    const half8_t hz = {0, 0, 0, 0, 0, 0, 0, 0};

    // ---- layer 1 via MFMA (k=8 zero-padded to K=32) ----
    half8_t a0 = hz, a1 = hz;
    if (q == 0) {
        int ci0 = e0 + m0 + fm;
        if (ci0 < E) {
            int e = eid[ci0];
            float4 p0 = *(const float4*)(rad + (size_t)e * 8);
            float4 p1 = *(const float4*)(rad + (size_t)e * 8 + 4);
            a0 = (half8_t){(f16)p0.x, (f16)p0.y, (f16)p0.z, (f16)p0.w,
                           (f16)p1.x, (f16)p1.y, (f16)p1.z, (f16)p1.w};
        }
        int ci1 = e0 + m0 + 16 + fm;
        if (ci1 < E) {
            int e = eid[ci1];
            float4 p0 = *(const float4*)(rad + (size_t)e * 8);
            float4 p1 = *(const float4*)(rad + (size_t)e * 8 + 4);
            a1 = (half8_t){(f16)p0.x, (f16)p0.y, (f16)p0.z, (f16)p0.w,
                           (f16)p1.x, (f16)p1.y, (f16)p1.z, (f16)p1.w};
        }
    }
#pragma unroll
    for (int nt = 0; nt < 4; ++nt) {
        half8_t b = *(const half8_t*)(wT1 + ((nt * 16 + fm) << 5) + q * 8);
        f32x4 c0 = {0.f, 0.f, 0.f, 0.f};
        c0 = __builtin_amdgcn_mfma_f32_16x16x32_f16(a0, b, c0, 0, 0, 0);
        f32x4 c1 = {0.f, 0.f, 0.f, 0.f};
        c1 = __builtin_amdgcn_mfma_f32_16x16x32_f16(a1, b, c1, 0, 0, 0);
#pragma unroll
        for (int r = 0; r < 4; ++r) {
            act[m0 + q * 4 + r][nt * 16 + fm]      = (f16)silu_f(c0[r]);
            act[m0 + 16 + q * 4 + r][nt * 16 + fm] = (f16)silu_f(c1[r]);
        }
    }

    auto loadA = [&](int mbase, int kc) -> half8_t {
        return *(const half8_t*)&act[mbase + fm][kc + q * 8];
    };

    // ---- layers 2, 3: B from global wT (L1-hot) ----
    const f16* wts[2] = {wT2, wT3};
#pragma unroll
    for (int L = 0; L < 2; ++L) {
        const f16* wT = wts[L];
        half8_t a00 = loadA(m0, 0),      a01 = loadA(m0, 32);
        half8_t a10 = loadA(m0 + 16, 0), a11 = loadA(m0 + 16, 32);
#pragma unroll
        for (int nt = 0; nt < 4; ++nt) {
            const f16* wr = wT + ((nt * 16 + fm) << 6);
            half8_t b0 = *(const half8_t*)(wr + q * 8);
            half8_t b1 = *(const half8_t*)(wr + 32 + q * 8);
            f32x4 c0 = {0.f, 0.f, 0.f, 0.f};
            c0 = __builtin_amdgcn_mfma_f32_16x16x32_f16(a00, b0, c0, 0, 0, 0);
            c0 = __builtin_amdgcn_mfma_f32_16x16x32_f16(a01, b1, c0, 0, 0, 0);
            f32x4 c1 = {0.f, 0.f, 0.f, 0.f};
            c1 = __builtin_amdgcn_mfma_f32_16x16x32_f16(a10, b0, c1, 0, 0, 0);
            c1 = __builtin_amdgcn_mfma_f32_16x16x32_f16(a11, b1, c1, 0, 0, 0);
#pragma unroll
            for (int r = 0; r < 4; ++r) {
                act[m0 + q * 4 + r][nt * 16 + fm]      = (f16)silu_f(c0[r]);
                act[m0 + 16 + q * 4 + r][nt * 16 + fm] = (f16)silu_f(c1[r]);
            }
        }
    }

    // ---- layer 4: 4 output chunks (one per irrep l) ----
    half8_t A00 = loadA(m0, 0),      A01 = loadA(m0, 32);
    half8_t A10 = loadA(m0 + 16, 0), A11 = loadA(m0 + 16, 32);

#pragma unroll
    for (int l = 0; l < 4; ++l) {
        const f16* wT = wT4 + (l << 12);
#pragma unroll
        for (int nt = 0; nt < 4; ++nt) {
            const f16* wr = wT + ((nt * 16 + fm) << 6);
            half8_t b0 = *(const half8_t*)(wr + q * 8);
            half8_t b1 = *(const half8_t*)(wr + 32 + q * 8);
            f32x4 c0 = {0.f, 0.f, 0.f, 0.f};
            c0 = __builtin_amdgcn_mfma_f32_16x16x32_f16(A00, b0, c0, 0, 0, 0);
            c0 = __builtin_amdgcn_mfma_f32_16x16x32_f16(A01, b1, c0, 0, 0, 0);
            f32x4 c1 = {0.f, 0.f, 0.f, 0.f};
            c1 = __builtin_amdgcn_mfma_f32_16x16x32_f16(A10, b0, c1, 0, 0, 0);
            c1 = __builtin_amdgcn_mfma_f32_16x16x32_f16(A11, b1, c1, 0, 0, 0);
#pragma unroll
            for (int r = 0; r < 4; ++r) {
                act[m0 + q * 4 + r][nt * 16 + fm]      = (f16)c0[r];
                act[m0 + 16 + q * 4 + r][nt * 16 + fm] = (f16)c1[r];
            }
        }
        // wave-private reshuffle -> coalesced half8 stores (rows = CSR index)
#pragma unroll
        for (int it = 0; it < 4; ++it) {
            int row = (lane >> 3) + it * 8;
            int ci = e0 + m0 + row;
            if (ci < E) {
                half8_t v = *(const half8_t*)&act[m0 + row][(lane & 7) * 8];
                *(half8_t*)&mixp[(size_t)ci * 256 + l * 64 + (lane & 7) * 8] = v;
            }
        }
    }
}

// ---------------- K2: gather, 1 node/wave, packed-fp32 down-proj epilogue ------
__global__ __launch_bounds__(256) void k_gather(const float* __restrict__ x,
        const f16* __restrict__ mixp, const float* __restrict__ yb,
        const int* __restrict__ sndp, const int* __restrict__ off,
        const float* __restrict__ Wd, float* __restrict__ out, int N) {
    __shared__ float sbuf[4][64 * 20];
    int wv = threadIdx.x >> 6;
    int lane = threadIdx.x & 63;
    int n = blockIdx.x * 4 + wv;
    if (n >= N) return;

    float o[16];
#pragma unroll
    for (int i = 0; i < 16; ++i) o[i] = 0.f;

    auto process = [&](int i) {
        int s = sndp[i];
        const float* yr = yb + (size_t)i * 16;
        float4 A = *(const float4*)(yr + 0);
        float4 B = *(const float4*)(yr + 4);
        float4 Cv = *(const float4*)(yr + 8);
        float4 D = *(const float4*)(yr + 12);
        float sf = x[(size_t)s * 64 + lane];
        const f16* mr = mixp + (size_t)i * 256;
        float t0 = sf * (float)mr[lane];
        float t1 = sf * (float)mr[64 + lane];
        float t2 = sf * (float)mr[128 + lane];
        float t3 = sf * (float)mr[192 + lane];
        o[0]  += t0;
        o[1]  += t1 * A.y;
        o[2]  += t1 * A.z;
        o[3]  += t1 * A.w;
        o[4]  += t2 * B.x;
        o[5]  += t2 * B.y;
        o[6]  += t2 * B.z;
        o[7]  += t2 * B.w;
        o[8]  += t2 * Cv.x;
        o[9]  += t3 * Cv.y;
        o[10] += t3 * Cv.z;
        o[11] += t3 * Cv.w;
        o[12] += t3 * D.x;
        o[13] += t3 * D.y;
        o[14] += t3 * D.z;
        o[15] += t3 * D.w;
    };

    int beg = off[n], end = off[n + 1];
    int i = beg;
    for (; i + 1 < end; i += 2) { process(i); process(i + 1); }
    if (i < end) process(i);

    // wave-private transpose: lane's o[16] -> sw[lane*20 + m], b128 writes
    float* sw = sbuf[wv];
#pragma unroll
    for (int a = 0; a < 4; ++a) {
        f32x4 vq = {o[4 * a + 0], o[4 * a + 1], o[4 * a + 2], o[4 * a + 3]};
        *(f32x4*)&sw[lane * 20 + 4 * a] = vq;
    }

    // down-proj: per c, 4 b128 broadcasts + packed-f32 fma quads
    f32x4 dA = {0.f, 0.f, 0.f, 0.f}, dB = dA, dC = dA, dD = dA;
#pragma unroll 1
    for (int c = 0; c < 64; ++c) {
        f32x4 q0 = *(const f32x4*)&sw[c * 20 + 0];
        f32x4 q1 = *(const f32x4*)&sw[c * 20 + 4];
        f32x4 q2 = *(const f32x4*)&sw[c * 20 + 8];
        f32x4 q3 = *(const f32x4*)&sw[c * 20 + 12];
        float w0  = Wd[c * 64 + lane];
        float w1r = Wd[4096 + c * 64 + lane];
        float w2r = Wd[8192 + c * 64 + lane];
        float w3r = Wd[12288 + c * 64 + lane];
        f32x4 wA = {w0, w1r, w1r, w1r};
        f32x4 wC4 = {w2r, w3r, w3r, w3r};
        dA += q0 * wA;
        dB += q1 * w2r;
        dC += q2 * wC4;
        dD += q3 * w3r;
    }

    float* outr = out + (size_t)n * 1024;
    outr[lane] = 0.25f * dA[0];
#pragma unroll
    for (int m = 0; m < 3; ++m) outr[64 + lane * 3 + m] = 0.25f * dA[1 + m];
    outr[256 + lane * 5 + 0] = 0.25f * dB[0];
    outr[256 + lane * 5 + 1] = 0.25f * dB[1];
    outr[256 + lane * 5 + 2] = 0.25f * dB[2];
    outr[256 + lane * 5 + 3] = 0.25f * dB[3];
    outr[256 + lane * 5 + 4] = 0.25f * dC[0];
    outr[576 + lane * 7 + 0] = 0.25f * dC[1];
    outr[576 + lane * 7 + 1] = 0.25f * dC[2];
    outr[576 + lane * 7 + 2] = 0.25f * dC[3];
    outr[576 + lane * 7 + 3] = 0.25f * dD[0];
    outr[576 + lane * 7 + 4] = 0.25f * dD[1];
    outr[576 + lane * 7 + 5] = 0.25f * dD[2];
    outr[576 + lane * 7 + 6] = 0.25f * dD[3];
}

extern "C" void kernel_launch(void* const* d_in, const int* in_sizes, int n_in,
                              void* d_out, int out_size, void* d_ws, size_t ws_size,
                              hipStream_t stream) {
    const float* vectors    = (const float*)d_in[0];
    const float* node_feats = (const float*)d_in[1];
    const float* radial     = (const float*)d_in[2];
    const float* W_up       = (const float*)d_in[3];
    const float* w1         = (const float*)d_in[4];
    const float* w2         = (const float*)d_in[5];
    const float* w3         = (const float*)d_in[6];
    const float* w4         = (const float*)d_in[7];
    const float* Wd         = (const float*)d_in[8];
    const int*   snd        = (const int*)d_in[9];
    const int*   rcv        = (const int*)d_in[10];
    float* out = (float*)d_out;

    int E = in_sizes[9];
    int N = in_sizes[1] / CC;

    // ws: wT1[2048]h | wT2[4096]h | wT3[4096]h | wT4[16384]h | x [N*64]f |
    //     yb [E*16]f | mixp [E*256]h | cnt [N] | off [N+1] | cur [N] | eid [E] | sndp [E]
    f16*   wT1  = (f16*)d_ws;
    f16*   wT2  = wT1 + 2048;
    f16*   wT3  = wT2 + 4096;
    f16*   wT4  = wT3 + 4096;
    float* x    = (float*)(wT4 + 16384);
    float* yb   = x + (size_t)N * 64;
    f16*   mixp = (f16*)(yb + (size_t)E * 16);
    int*   cnt  = (int*)(mixp + (size_t)E * 256);
    int*   off  = cnt + N;
    int*   cur  = off + (N + 1);
    int*   eid  = cur + N;
    int*   sndp = eid + E;

    hipMemsetAsync(cnt, 0, (size_t)N * sizeof(int), stream);

    k_wt<<<(26624 + 255) / 256, 256, 0, stream>>>(w1, w2, w3, w4, wT1, wT2, wT3, wT4);
    k_up<<<(N * CC + 255) / 256, 256, 0, stream>>>(node_feats, W_up, x, N);
    k_hist<<<(E + 255) / 256, 256, 0, stream>>>(rcv, cnt, E);
    k_scan<<<1, 1024, 0, stream>>>(cnt, off, cur, N);
    k_fill<<<(E + 255) / 256, 256, 0, stream>>>(rcv, snd, vectors, cur, eid, sndp, yb, E);
    k_mlp<<<(E + 127) / 128, 256, 0, stream>>>(radial, wT1, wT2, wT3, wT4, eid, mixp, E);
    k_gather<<<(N + 3) / 4, 256, 0, stream>>>(x, mixp, yb, sndp, off, Wd, out, N);
}